// Round 6
// baseline (841.021 us; speedup 1.0000x reference)
//
#include <hip/hip_runtime.h>

#define N_NODES 200000
#define N_EDGES 400000
#define N_GRAPHS 64
#define HDIM 128
#define INDIM 5
#define LN_EPS 1e-5f

typedef __attribute__((ext_vector_type(8))) short short8;
typedef __attribute__((ext_vector_type(4))) float f32x4;

__device__ __forceinline__ void split_bf(float v, short& h, short& l) {
    unsigned u = __builtin_bit_cast(unsigned, v);
    unsigned r = (u + 0x7FFFu + ((u >> 16) & 1u)) >> 16;
    h = (short)r;
    float hf = __builtin_bit_cast(float, r << 16);
    float d = v - hf;
    unsigned u2 = __builtin_bit_cast(unsigned, d);
    unsigned r2 = (u2 + 0x7FFFu + ((u2 >> 16) & 1u)) >> 16;
    l = (short)r2;
}

__device__ __forceinline__ short to_bf(float v) {
    unsigned u = __builtin_bit_cast(unsigned, v);
    return (short)((u + 0x7FFFu + ((u >> 16) & 1u)) >> 16);
}

// ---------------- CSR build ----------------

__global__ void hist_kernel(const int* __restrict__ ei, int* __restrict__ deg) {
    int e = blockIdx.x * blockDim.x + threadIdx.x;
    if (e < N_EDGES) atomicAdd(&deg[ei[N_EDGES + e]], 1);
}

#define SCAN_CHUNK 1024
#define SCAN_BLOCKS ((N_NODES + SCAN_CHUNK - 1) / SCAN_CHUNK)  // 196

__global__ __launch_bounds__(256) void scan_phaseA(const int* __restrict__ deg, int* __restrict__ bsums) {
    __shared__ int red[256];
    int t = threadIdx.x;
    int base = blockIdx.x * SCAN_CHUNK + t * 4;
    int s = 0;
#pragma unroll
    for (int k = 0; k < 4; ++k) {
        int i = base + k;
        s += (i < N_NODES) ? deg[i] : 0;
    }
    red[t] = s;
    __syncthreads();
    for (int off = 128; off; off >>= 1) {
        if (t < off) red[t] += red[t + off];
        __syncthreads();
    }
    if (t == 0) bsums[blockIdx.x] = red[0];
}

// parallel exclusive scan of bsums (196 entries) in one block
__global__ __launch_bounds__(256) void scan_phaseB(int* __restrict__ bsums, int* __restrict__ row_ptr) {
    __shared__ int s[256];
    int t = threadIdx.x;
    int v = (t < SCAN_BLOCKS) ? bsums[t] : 0;
    s[t] = v;
    __syncthreads();
    for (int off = 1; off < 256; off <<= 1) {
        int add = (t >= off) ? s[t - off] : 0;
        __syncthreads();
        s[t] += add;
        __syncthreads();
    }
    if (t < SCAN_BLOCKS) bsums[t] = s[t] - v;  // exclusive
    if (t == SCAN_BLOCKS - 1) row_ptr[N_NODES] = s[t];
}

__global__ __launch_bounds__(256) void scan_phaseC(const int* __restrict__ deg,
                                                   const int* __restrict__ bsums,
                                                   int* __restrict__ row_ptr) {
    __shared__ int ts[256];
    int t = threadIdx.x;
    int base = blockIdx.x * SCAN_CHUNK + t * 4;
    int v[4];
    int s = 0;
#pragma unroll
    for (int k = 0; k < 4; ++k) {
        int i = base + k;
        v[k] = (i < N_NODES) ? deg[i] : 0;
        s += v[k];
    }
    ts[t] = s;
    __syncthreads();
    for (int off = 1; off < 256; off <<= 1) {
        int add = (t >= off) ? ts[t - off] : 0;
        __syncthreads();
        ts[t] += add;
        __syncthreads();
    }
    int run = bsums[blockIdx.x] + ts[t] - s;
#pragma unroll
    for (int k = 0; k < 4; ++k) {
        int i = base + k;
        if (i < N_NODES) row_ptr[i] = run;
        run += v[k];
    }
}

__global__ void scatter_kernel(const int* __restrict__ ei, const float* __restrict__ ea,
                               const int* __restrict__ row_ptr, int* __restrict__ cursor,
                               int* __restrict__ csr_src, float* __restrict__ csr_val) {
    int e = blockIdx.x * blockDim.x + threadIdx.x;
    if (e >= N_EDGES) return;
    int d = ei[N_EDGES + e];
    int pos = atomicAdd(&cursor[d], 1);
    int slot = row_ptr[d] + pos;
    csr_src[slot] = ei[e];
    csr_val[slot] = ea[e];
}

// ---------------- Weight packing into MFMA B-fragment order (bf16 hi) ----------------
__global__ void pack_w(const float* __restrict__ W, short* __restrict__ hi, int din, int KP) {
    int idx = blockIdx.x * 256 + threadIdx.x;
    if (idx >= KP * 128) return;
    int j = idx & 7;
    int lane = (idx >> 3) & 63;
    int rest = idx >> 9;
    int KS = KP >> 5;
    int kstep = rest % KS;
    int tile = rest / KS;
    int k = kstep * 32 + ((lane >> 4) * 8) + j;
    int n = tile * 16 + (lane & 15);
    float v = (k < din) ? W[k * 128 + n] : 0.f;
    hi[idx] = to_bf(v);
}

// ---------------- Fused layer: edge-parallel gather + MFMA MLP + LN + ReLU (+pool) ----------------
#define LDA 132
template <int KP1, bool POOL>
__global__ __launch_bounds__(256, 4) void layer_fused(
    const float* __restrict__ xin, const int* __restrict__ row_ptr,
    const int* __restrict__ csr_src, const float* __restrict__ csr_val,
    const float* __restrict__ ew, const float* __restrict__ eb,
    const short* __restrict__ w1h, const float* __restrict__ b1,
    const short* __restrict__ w2h, const float* __restrict__ b2,
    const float* __restrict__ g, const float* __restrict__ bt,
    float* __restrict__ xout,
    const int* __restrict__ batch, float* __restrict__ pool, int* __restrict__ cnt) {
    __shared__ float A[64 * LDA];
    __shared__ int rp[65];
    __shared__ int bidx[64];
    __shared__ float EWs[128], EBs[128];
    union Scratch {
        struct { int esrc[256]; float eval[256]; unsigned char erow[256]; } gth;
        struct { float psum[4][64]; float psq[4][64]; float lmu[64]; float linv[64]; } ln;
    };
    __shared__ Scratch u;

    int tid = threadIdx.x;
    int node0 = blockIdx.x * 64;

    if (tid < 65) rp[tid] = row_ptr[node0 + tid];
    if (POOL && tid < 64) bidx[tid] = batch[node0 + tid];

    if (KP1 == 128) {
        // stage ew/eb
        if (tid >= 64 && tid < 96) *(float4*)&EWs[(tid - 64) * 4] = *(const float4*)&ew[(tid - 64) * 4];
        else if (tid >= 96 && tid < 128) *(float4*)&EBs[(tid - 96) * 4] = *(const float4*)&eb[(tid - 96) * 4];
        // init A rows with x[node]
#pragma unroll
        for (int i = 0; i < 8; ++i) {
            int g4 = tid + 256 * i;  // 2048 float4s = 64 rows x 32 groups
            int row = g4 >> 5, col = (g4 & 31) * 4;
            *(float4*)&A[row * LDA + col] = *(const float4*)&xin[(size_t)(node0 + row) * 128 + col];
        }
        __syncthreads();

        // edge-parallel gather over the block's contiguous CSR range
        int e0 = rp[0], e1 = rp[64];
        for (int base = e0; base < e1; base += 256) {
            int nE = min(256, e1 - base);
            if (tid < nE) {
                int e = base + tid;
                u.gth.esrc[tid] = csr_src[e];
                u.gth.eval[tid] = csr_val[e];
                int lo = 0, hi = 64;
#pragma unroll
                for (int it = 0; it < 6; ++it) {
                    int mid = (lo + hi) >> 1;
                    bool cge = (rp[mid] <= e);
                    lo = cge ? mid : lo;
                    hi = cge ? hi : mid;
                }
                u.gth.erow[tid] = (unsigned char)lo;
            }
            __syncthreads();
            int nw = nE * 16;  // (edge, 8-channel group) work items
            for (int i = tid; i < nw; i += 256) {
                int le = i >> 4, c = (i & 15) * 8;
                int s = u.gth.esrc[le];
                float a = u.gth.eval[le];
                int row = u.gth.erow[le];
                float4 x0 = *(const float4*)&xin[(size_t)s * 128 + c];
                float4 x1 = *(const float4*)&xin[(size_t)s * 128 + c + 4];
                float4 w0 = *(float4*)&EWs[c], w1v = *(float4*)&EWs[c + 4];
                float4 q0 = *(float4*)&EBs[c], q1 = *(float4*)&EBs[c + 4];
                float* ap = &A[row * LDA + c];
                unsafeAtomicAdd(ap + 0, fmaxf(x0.x + a * w0.x + q0.x, 0.f));
                unsafeAtomicAdd(ap + 1, fmaxf(x0.y + a * w0.y + q0.y, 0.f));
                unsafeAtomicAdd(ap + 2, fmaxf(x0.z + a * w0.z + q0.z, 0.f));
                unsafeAtomicAdd(ap + 3, fmaxf(x0.w + a * w0.w + q0.w, 0.f));
                unsafeAtomicAdd(ap + 4, fmaxf(x1.x + a * w1v.x + q1.x, 0.f));
                unsafeAtomicAdd(ap + 5, fmaxf(x1.y + a * w1v.y + q1.y, 0.f));
                unsafeAtomicAdd(ap + 6, fmaxf(x1.z + a * w1v.z + q1.z, 0.f));
                unsafeAtomicAdd(ap + 7, fmaxf(x1.w + a * w1v.w + q1.w, 0.f));
            }
            __syncthreads();
        }
    } else {
        // din = 5: per-node serial gather (tiny rows, input x is 4 MB -> cache-resident)
        __syncthreads();
        if (tid < 64) {
            int node = node0 + tid;
            float w[INDIM], bb[INDIM], acc[INDIM];
#pragma unroll
            for (int j = 0; j < INDIM; ++j) {
                w[j] = ew[j];
                bb[j] = eb[j];
                acc[j] = xin[node * INDIM + j];
            }
            int beg = rp[tid], end = rp[tid + 1];
            for (int e = beg; e < end; ++e) {
                int s = csr_src[e];
                float a = csr_val[e];
#pragma unroll
                for (int j = 0; j < INDIM; ++j)
                    acc[j] += fmaxf(xin[s * INDIM + j] + a * w[j] + bb[j], 0.f);
            }
#pragma unroll
            for (int j = 0; j < INDIM; ++j) A[tid * LDA + j] = acc[j];
#pragma unroll
            for (int j = INDIM; j < 32; ++j) A[tid * LDA + j] = 0.f;
        }
    }
    __syncthreads();

    int wv = tid >> 6, lane = tid & 63;
    int mrow = lane & 15, q = lane >> 4;
    int arow = wv * 16 + mrow;

    float b1v[8], b2v[8];
#pragma unroll
    for (int t = 0; t < 8; ++t) {
        b1v[t] = b1[t * 16 + mrow];
        b2v[t] = b2[t * 16 + mrow];
    }

    const short8* w1p = (const short8*)w1h;
    const short8* w2p = (const short8*)w2h;

    // ---- GEMM1 (exact-A hi/lo x bf16-B) ----
    f32x4 acc[8];
#pragma unroll
    for (int t = 0; t < 8; ++t) acc[t] = (f32x4){0.f, 0.f, 0.f, 0.f};
    constexpr int KS1 = KP1 / 32;
#pragma unroll
    for (int ks = 0; ks < KS1; ++ks) {
        short8 bh[8];
#pragma unroll
        for (int t = 0; t < 8; ++t) bh[t] = w1p[((size_t)t * KS1 + ks) * 64 + lane];
        float4 v0 = *(float4*)&A[arow * LDA + ks * 32 + q * 8];
        float4 v1 = *(float4*)&A[arow * LDA + ks * 32 + q * 8 + 4];
        float av[8] = {v0.x, v0.y, v0.z, v0.w, v1.x, v1.y, v1.z, v1.w};
        short8 ah, al;
#pragma unroll
        for (int j = 0; j < 8; ++j) {
            short h, l;
            split_bf(av[j], h, l);
            ah[j] = h;
            al[j] = l;
        }
#pragma unroll
        for (int t = 0; t < 8; ++t) {
            acc[t] = __builtin_amdgcn_mfma_f32_16x16x32_bf16(ah, bh[t], acc[t], 0, 0, 0);
            acc[t] = __builtin_amdgcn_mfma_f32_16x16x32_bf16(al, bh[t], acc[t], 0, 0, 0);
        }
    }
#pragma unroll
    for (int t = 0; t < 8; ++t)
#pragma unroll
        for (int r = 0; r < 4; ++r) {
            int row = wv * 16 + q * 4 + r;
            int col = t * 16 + mrow;
            A[row * LDA + col] = fmaxf(acc[t][r] + b1v[t], 0.f);
        }

    // ---- GEMM2 (K = 128) ----
#pragma unroll
    for (int t = 0; t < 8; ++t) acc[t] = (f32x4){0.f, 0.f, 0.f, 0.f};
#pragma unroll
    for (int ks = 0; ks < 4; ++ks) {
        short8 bh[8];
#pragma unroll
        for (int t = 0; t < 8; ++t) bh[t] = w2p[((size_t)t * 4 + ks) * 64 + lane];
        float4 v0 = *(float4*)&A[arow * LDA + ks * 32 + q * 8];
        float4 v1 = *(float4*)&A[arow * LDA + ks * 32 + q * 8 + 4];
        float av[8] = {v0.x, v0.y, v0.z, v0.w, v1.x, v1.y, v1.z, v1.w};
        short8 ah, al;
#pragma unroll
        for (int j = 0; j < 8; ++j) {
            short h, l;
            split_bf(av[j], h, l);
            ah[j] = h;
            al[j] = l;
        }
#pragma unroll
        for (int t = 0; t < 8; ++t) {
            acc[t] = __builtin_amdgcn_mfma_f32_16x16x32_bf16(ah, bh[t], acc[t], 0, 0, 0);
            acc[t] = __builtin_amdgcn_mfma_f32_16x16x32_bf16(al, bh[t], acc[t], 0, 0, 0);
        }
    }
#pragma unroll
    for (int t = 0; t < 8; ++t)
#pragma unroll
        for (int r = 0; r < 4; ++r) {
            int row = wv * 16 + q * 4 + r;
            int col = t * 16 + mrow;
            A[row * LDA + col] = acc[t][r] + b2v[t];
        }
    __syncthreads();

    // ---- LayerNorm stats ----
    {
        int row = tid & 63, seg = tid >> 6;
        float s = 0.f, sq = 0.f;
#pragma unroll
        for (int i = 0; i < 8; ++i) {
            float4 v = *(float4*)&A[row * LDA + seg * 32 + i * 4];
            s += v.x + v.y + v.z + v.w;
            sq += v.x * v.x + v.y * v.y + v.z * v.z + v.w * v.w;
        }
        u.ln.psum[seg][row] = s;
        u.ln.psq[seg][row] = sq;
    }
    __syncthreads();
    if (tid < 64) {
        float s = u.ln.psum[0][tid] + u.ln.psum[1][tid] + u.ln.psum[2][tid] + u.ln.psum[3][tid];
        float sq = u.ln.psq[0][tid] + u.ln.psq[1][tid] + u.ln.psq[2][tid] + u.ln.psq[3][tid];
        float mu = s * (1.f / HDIM);
        float var = sq * (1.f / HDIM) - mu * mu;
        u.ln.lmu[tid] = mu;
        u.ln.linv[tid] = rsqrtf(var + LN_EPS);
    }
    __syncthreads();

    // ---- scale/shift + ReLU ----
    int colbase = (tid * 4) & 127;
    float4 gv = *(const float4*)&g[colbase];
    float4 btv = *(const float4*)&bt[colbase];
#pragma unroll
    for (int i = 0; i < 8; ++i) {
        int row = (tid >> 5) + 8 * i;
        float4 v = *(float4*)&A[row * LDA + colbase];
        float mu = u.ln.lmu[row], inv = u.ln.linv[row];
        float4 o;
        o.x = fmaxf((v.x - mu) * inv * gv.x + btv.x, 0.f);
        o.y = fmaxf((v.y - mu) * inv * gv.y + btv.y, 0.f);
        o.z = fmaxf((v.z - mu) * inv * gv.z + btv.z, 0.f);
        o.w = fmaxf((v.w - mu) * inv * gv.w + btv.w, 0.f);
        if (POOL) {
            *(float4*)&A[row * LDA + colbase] = o;
        } else {
            *(float4*)&xout[(size_t)(node0 + row) * 128 + colbase] = o;
        }
    }

    // ---- fused pooling (layer 2) ----
    if (POOL) {
        __syncthreads();
        if (tid < 128) {
            int col = tid;
            float acc2 = 0.f;
            int cur = bidx[0];
            for (int r = 0; r < 64; ++r) {
                int gi = bidx[r];
                if (gi != cur) {
                    unsafeAtomicAdd(&pool[cur * HDIM + col], acc2);
                    acc2 = 0.f;
                    cur = gi;
                }
                acc2 += A[r * LDA + col];
            }
            unsafeAtomicAdd(&pool[cur * HDIM + col], acc2);
        } else if (tid == 255) {
            int cur = bidx[0], c = 0;
            for (int r = 0; r < 64; ++r) {
                if (bidx[r] != cur) {
                    atomicAdd(&cnt[cur], c);
                    c = 0;
                    cur = bidx[r];
                }
                ++c;
            }
            atomicAdd(&cnt[cur], c);
        }
    }
}

__global__ void pool_final(const float* __restrict__ pool, const int* __restrict__ cnt,
                           float* __restrict__ out) {
    int g = blockIdx.x, j = threadIdx.x;
    float add = pool[g * HDIM + j];
    float c = (float)max(cnt[g], 1);
    out[g * (2 * HDIM) + j] = add / c;
    out[g * (2 * HDIM) + HDIM + j] = add;
}

extern "C" void kernel_launch(void* const* d_in, const int* in_sizes, int n_in,
                              void* d_out, int out_size, void* d_ws, size_t ws_size,
                              hipStream_t stream) {
    const float* x_in = (const float*)d_in[0];
    const int* ei = (const int*)d_in[1];
    const float* ea = (const float*)d_in[2];
    const int* batch = (const int*)d_in[3];
    const float* P[24];
    for (int i = 0; i < 24; ++i) P[i] = (const float*)d_in[4 + i];
    // per layer l (base 8l): 0=ew 1=eb 2=w1 3=b1 4=w2 5=b2 6=g 7=bt

    float* x_a = (float*)d_ws;                            // N*128
    float* x_b = x_a + (size_t)N_NODES * HDIM;            // N*128
    float* pool = x_b + (size_t)N_NODES * HDIM;           // G*128 } zeroed
    int* cnt = (int*)(pool + N_GRAPHS * HDIM);            // G     } together
    int* deg = cnt + N_GRAPHS;                            // N     } (one
    int* cursor = deg + N_NODES;                          // N     } memset)
    int* row_ptr = cursor + N_NODES;                      // N+1
    int* bsums = row_ptr + N_NODES + 1;                   // pad 256
    int* csr_src = bsums + 256;                           // E
    float* csr_val = (float*)(csr_src + N_EDGES);         // E
    short* wp = (short*)(((uintptr_t)(csr_val + N_EDGES) + 15) & ~(uintptr_t)15);
    float* out = (float*)d_out;

    short *w1h[3], *w2h[3];
    for (int l = 0; l < 3; ++l) {
        w1h[l] = wp + (size_t)l * 32768;
        w2h[l] = w1h[l] + 16384;
    }

    // ---- single memset: pool + cnt + deg + cursor ----
    hipMemsetAsync(pool, 0,
                   (N_GRAPHS * HDIM + N_GRAPHS + 2 * N_NODES) * sizeof(int), stream);

    // ---- CSR build ----
    hist_kernel<<<(N_EDGES + 255) / 256, 256, 0, stream>>>(ei, deg);
    scan_phaseA<<<SCAN_BLOCKS, 256, 0, stream>>>(deg, bsums);
    scan_phaseB<<<1, 256, 0, stream>>>(bsums, row_ptr);
    scan_phaseC<<<SCAN_BLOCKS, 256, 0, stream>>>(deg, bsums, row_ptr);
    scatter_kernel<<<(N_EDGES + 255) / 256, 256, 0, stream>>>(ei, ea, row_ptr, cursor, csr_src, csr_val);

    // ---- pack weights (bf16 hi) ----
    pack_w<<<16, 256, 0, stream>>>(P[2], w1h[0], INDIM, 32);
    pack_w<<<64, 256, 0, stream>>>(P[4], w2h[0], 128, 128);
    for (int l = 1; l < 3; ++l) {
        pack_w<<<64, 256, 0, stream>>>(P[8 * l + 2], w1h[l], 128, 128);
        pack_w<<<64, 256, 0, stream>>>(P[8 * l + 4], w2h[l], 128, 128);
    }

    // ---- fused layers ----
    layer_fused<32, false><<<N_NODES / 64, 256, 0, stream>>>(
        x_in, row_ptr, csr_src, csr_val, P[0], P[1],
        w1h[0], P[3], w2h[0], P[5], P[6], P[7], x_a, nullptr, nullptr, nullptr);
    layer_fused<128, false><<<N_NODES / 64, 256, 0, stream>>>(
        x_a, row_ptr, csr_src, csr_val, P[8], P[9],
        w1h[1], P[11], w2h[1], P[13], P[14], P[15], x_b, nullptr, nullptr, nullptr);
    layer_fused<128, true><<<N_NODES / 64, 256, 0, stream>>>(
        x_b, row_ptr, csr_src, csr_val, P[16], P[17],
        w1h[2], P[19], w2h[2], P[21], P[22], P[23], nullptr, batch, pool, cnt);

    pool_final<<<N_GRAPHS, HDIM, 0, stream>>>(pool, cnt, out);
}

// Round 7
// 542.289 us; speedup vs baseline: 1.5509x; 1.5509x over previous
//
#include <hip/hip_runtime.h>

#define N_NODES 200000
#define N_EDGES 400000
#define N_GRAPHS 64
#define HDIM 128
#define INDIM 5
#define LN_EPS 1e-5f

typedef __attribute__((ext_vector_type(8))) short short8;
typedef __attribute__((ext_vector_type(4))) float f32x4;

__device__ __forceinline__ void split_bf(float v, short& h, short& l) {
    unsigned u = __builtin_bit_cast(unsigned, v);
    unsigned r = (u + 0x7FFFu + ((u >> 16) & 1u)) >> 16;
    h = (short)r;
    float hf = __builtin_bit_cast(float, r << 16);
    float d = v - hf;
    unsigned u2 = __builtin_bit_cast(unsigned, d);
    unsigned r2 = (u2 + 0x7FFFu + ((u2 >> 16) & 1u)) >> 16;
    l = (short)r2;
}

__device__ __forceinline__ short to_bf(float v) {
    unsigned u = __builtin_bit_cast(unsigned, v);
    return (short)((u + 0x7FFFu + ((u >> 16) & 1u)) >> 16);
}

// ---------------- CSR build ----------------

__global__ void hist_kernel(const int* __restrict__ ei, int* __restrict__ deg) {
    int e = blockIdx.x * blockDim.x + threadIdx.x;
    if (e < N_EDGES) atomicAdd(&deg[ei[N_EDGES + e]], 1);
}

#define SCAN_CHUNK 1024
#define SCAN_BLOCKS ((N_NODES + SCAN_CHUNK - 1) / SCAN_CHUNK)  // 196

__global__ __launch_bounds__(256) void scan_phaseA(const int* __restrict__ deg, int* __restrict__ bsums) {
    __shared__ int red[256];
    int t = threadIdx.x;
    int base = blockIdx.x * SCAN_CHUNK + t * 4;
    int s = 0;
#pragma unroll
    for (int k = 0; k < 4; ++k) {
        int i = base + k;
        s += (i < N_NODES) ? deg[i] : 0;
    }
    red[t] = s;
    __syncthreads();
    for (int off = 128; off; off >>= 1) {
        if (t < off) red[t] += red[t + off];
        __syncthreads();
    }
    if (t == 0) bsums[blockIdx.x] = red[0];
}

__global__ __launch_bounds__(256) void scan_phaseB(int* __restrict__ bsums, int* __restrict__ row_ptr) {
    __shared__ int s[256];
    int t = threadIdx.x;
    int v = (t < SCAN_BLOCKS) ? bsums[t] : 0;
    s[t] = v;
    __syncthreads();
    for (int off = 1; off < 256; off <<= 1) {
        int add = (t >= off) ? s[t - off] : 0;
        __syncthreads();
        s[t] += add;
        __syncthreads();
    }
    if (t < SCAN_BLOCKS) bsums[t] = s[t] - v;  // exclusive
    if (t == SCAN_BLOCKS - 1) row_ptr[N_NODES] = s[t];
}

__global__ __launch_bounds__(256) void scan_phaseC(const int* __restrict__ deg,
                                                   const int* __restrict__ bsums,
                                                   int* __restrict__ row_ptr) {
    __shared__ int ts[256];
    int t = threadIdx.x;
    int base = blockIdx.x * SCAN_CHUNK + t * 4;
    int v[4];
    int s = 0;
#pragma unroll
    for (int k = 0; k < 4; ++k) {
        int i = base + k;
        v[k] = (i < N_NODES) ? deg[i] : 0;
        s += v[k];
    }
    ts[t] = s;
    __syncthreads();
    for (int off = 1; off < 256; off <<= 1) {
        int add = (t >= off) ? ts[t - off] : 0;
        __syncthreads();
        ts[t] += add;
        __syncthreads();
    }
    int run = bsums[blockIdx.x] + ts[t] - s;
#pragma unroll
    for (int k = 0; k < 4; ++k) {
        int i = base + k;
        if (i < N_NODES) row_ptr[i] = run;
        run += v[k];
    }
}

__global__ void scatter_kernel(const int* __restrict__ ei, const float* __restrict__ ea,
                               const int* __restrict__ row_ptr, int* __restrict__ cursor,
                               int* __restrict__ csr_src, float* __restrict__ csr_val) {
    int e = blockIdx.x * blockDim.x + threadIdx.x;
    if (e >= N_EDGES) return;
    int d = ei[N_EDGES + e];
    int pos = atomicAdd(&cursor[d], 1);
    int slot = row_ptr[d] + pos;
    csr_src[slot] = ei[e];
    csr_val[slot] = ea[e];
}

// ---------------- Weight packing into MFMA B-fragment order (bf16 hi) ----------------
__global__ void pack_w(const float* __restrict__ W, short* __restrict__ hi, int din, int KP) {
    int idx = blockIdx.x * 256 + threadIdx.x;
    if (idx >= KP * 128) return;
    int j = idx & 7;
    int lane = (idx >> 3) & 63;
    int rest = idx >> 9;
    int KS = KP >> 5;
    int kstep = rest % KS;
    int tile = rest / KS;
    int k = kstep * 32 + ((lane >> 4) * 8) + j;
    int n = tile * 16 + (lane & 15);
    float v = (k < din) ? W[k * 128 + n] : 0.f;
    hi[idx] = to_bf(v);
}

// ---------------- Fused layer: row-parallel gather + MFMA MLP + LN + ReLU (+pool) ----------------
#define LDA 132
template <int KP1, bool POOL>
__global__ __launch_bounds__(256, 4) void layer_fused(
    const float* __restrict__ xin, const int* __restrict__ row_ptr,
    const int* __restrict__ csr_src, const float* __restrict__ csr_val,
    const float* __restrict__ ew, const float* __restrict__ eb,
    const short* __restrict__ w1h, const float* __restrict__ b1,
    const short* __restrict__ w2h, const float* __restrict__ b2,
    const float* __restrict__ g, const float* __restrict__ bt,
    float* __restrict__ xout,
    const int* __restrict__ batch, float* __restrict__ pool, int* __restrict__ cnt) {
    __shared__ float A[64 * LDA];
    __shared__ float EWs[128], EBs[128];
    __shared__ int bidx[64];
    union Scratch {
        float part[64][2][INDIM];  // layer-0 gather partials
        struct { float psum[4][64]; float psq[4][64]; float lmu[64]; float linv[64]; } ln;
    };
    __shared__ Scratch u;

    int tid = threadIdx.x;
    int node0 = blockIdx.x * 64;

    if (KP1 == 128) {
        // stage ew/eb; batch indices for pool layer
        if (tid < 32) *(float4*)&EWs[tid * 4] = *(const float4*)&ew[tid * 4];
        else if (tid < 64) *(float4*)&EBs[(tid - 32) * 4] = *(const float4*)&eb[(tid - 32) * 4];
        if (POOL && tid >= 64 && tid < 128) bidx[tid - 64] = batch[node0 + tid - 64];

        // gather: thread = (row, 32-channel quarter); acc in registers, no atomics
        int row = tid >> 2, qt = tid & 3, c0 = qt * 32;
        int node = node0 + row;
        const float* xn = &xin[(size_t)node * 128 + c0];
        float4 acc8[8];
#pragma unroll
        for (int j = 0; j < 8; ++j) acc8[j] = *(const float4*)&xn[j * 4];
        int beg = row_ptr[node], end = row_ptr[node + 1];
        __syncthreads();  // EWs/EBs ready
        for (int e = beg; e < end; ++e) {
            int s = csr_src[e];
            float a = csr_val[e];
            const float* xs = &xin[(size_t)s * 128 + c0];
            float4 xv[8];
#pragma unroll
            for (int j = 0; j < 8; ++j) xv[j] = *(const float4*)&xs[j * 4];
#pragma unroll
            for (int j = 0; j < 8; ++j) {
                float4 wv = *(float4*)&EWs[c0 + j * 4];
                float4 bv = *(float4*)&EBs[c0 + j * 4];
                acc8[j].x += fmaxf(fmaf(a, wv.x, xv[j].x + bv.x), 0.f);
                acc8[j].y += fmaxf(fmaf(a, wv.y, xv[j].y + bv.y), 0.f);
                acc8[j].z += fmaxf(fmaf(a, wv.z, xv[j].z + bv.z), 0.f);
                acc8[j].w += fmaxf(fmaf(a, wv.w, xv[j].w + bv.w), 0.f);
            }
        }
#pragma unroll
        for (int j = 0; j < 8; ++j) *(float4*)&A[row * LDA + c0 + j * 4] = acc8[j];
    } else {
        // layer 0 (din=5): 2 threads/row split the edge list; register partials
        int row = tid >> 2, qt = tid & 3;
        int node = node0 + row;
        if (qt < 2) {
            float w[INDIM], b[INDIM], acc[INDIM];
#pragma unroll
            for (int j = 0; j < INDIM; ++j) {
                w[j] = ew[j];
                b[j] = eb[j];
                acc[j] = 0.f;
            }
            int beg = row_ptr[node], end = row_ptr[node + 1];
            for (int e = beg + qt; e < end; e += 2) {
                int s = csr_src[e];
                float a = csr_val[e];
#pragma unroll
                for (int j = 0; j < INDIM; ++j)
                    acc[j] += fmaxf(fmaf(a, w[j], xin[s * INDIM + j] + b[j]), 0.f);
            }
#pragma unroll
            for (int j = 0; j < INDIM; ++j) u.part[row][qt][j] = acc[j];
        }
        __syncthreads();
        if (tid < 64) {
#pragma unroll
            for (int j = 0; j < INDIM; ++j)
                A[tid * LDA + j] = xin[(node0 + tid) * INDIM + j] + u.part[tid][0][j] + u.part[tid][1][j];
#pragma unroll
            for (int j = INDIM; j < 32; ++j) A[tid * LDA + j] = 0.f;
        }
    }
    __syncthreads();

    int wv = tid >> 6, lane = tid & 63;
    int mrow = lane & 15, q = lane >> 4;
    int arow = wv * 16 + mrow;

    float b1v[8], b2v[8];
#pragma unroll
    for (int t = 0; t < 8; ++t) {
        b1v[t] = b1[t * 16 + mrow];
        b2v[t] = b2[t * 16 + mrow];
    }

    const short8* w1p = (const short8*)w1h;
    const short8* w2p = (const short8*)w2h;

    // ---- GEMM1 (exact-A hi/lo x bf16-B) ----
    f32x4 acc[8];
#pragma unroll
    for (int t = 0; t < 8; ++t) acc[t] = (f32x4){0.f, 0.f, 0.f, 0.f};
    constexpr int KS1 = KP1 / 32;
#pragma unroll
    for (int ks = 0; ks < KS1; ++ks) {
        short8 bh[8];
#pragma unroll
        for (int t = 0; t < 8; ++t) bh[t] = w1p[((size_t)t * KS1 + ks) * 64 + lane];
        float4 v0 = *(float4*)&A[arow * LDA + ks * 32 + q * 8];
        float4 v1 = *(float4*)&A[arow * LDA + ks * 32 + q * 8 + 4];
        float av[8] = {v0.x, v0.y, v0.z, v0.w, v1.x, v1.y, v1.z, v1.w};
        short8 ah, al;
#pragma unroll
        for (int j = 0; j < 8; ++j) {
            short h, l;
            split_bf(av[j], h, l);
            ah[j] = h;
            al[j] = l;
        }
#pragma unroll
        for (int t = 0; t < 8; ++t) {
            acc[t] = __builtin_amdgcn_mfma_f32_16x16x32_bf16(ah, bh[t], acc[t], 0, 0, 0);
            acc[t] = __builtin_amdgcn_mfma_f32_16x16x32_bf16(al, bh[t], acc[t], 0, 0, 0);
        }
    }
#pragma unroll
    for (int t = 0; t < 8; ++t)
#pragma unroll
        for (int r = 0; r < 4; ++r) {
            int row = wv * 16 + q * 4 + r;
            int col = t * 16 + mrow;
            A[row * LDA + col] = fmaxf(acc[t][r] + b1v[t], 0.f);
        }

    // ---- GEMM2 (K = 128) ----
#pragma unroll
    for (int t = 0; t < 8; ++t) acc[t] = (f32x4){0.f, 0.f, 0.f, 0.f};
#pragma unroll
    for (int ks = 0; ks < 4; ++ks) {
        short8 bh[8];
#pragma unroll
        for (int t = 0; t < 8; ++t) bh[t] = w2p[((size_t)t * 4 + ks) * 64 + lane];
        float4 v0 = *(float4*)&A[arow * LDA + ks * 32 + q * 8];
        float4 v1 = *(float4*)&A[arow * LDA + ks * 32 + q * 8 + 4];
        float av[8] = {v0.x, v0.y, v0.z, v0.w, v1.x, v1.y, v1.z, v1.w};
        short8 ah, al;
#pragma unroll
        for (int j = 0; j < 8; ++j) {
            short h, l;
            split_bf(av[j], h, l);
            ah[j] = h;
            al[j] = l;
        }
#pragma unroll
        for (int t = 0; t < 8; ++t) {
            acc[t] = __builtin_amdgcn_mfma_f32_16x16x32_bf16(ah, bh[t], acc[t], 0, 0, 0);
            acc[t] = __builtin_amdgcn_mfma_f32_16x16x32_bf16(al, bh[t], acc[t], 0, 0, 0);
        }
    }
#pragma unroll
    for (int t = 0; t < 8; ++t)
#pragma unroll
        for (int r = 0; r < 4; ++r) {
            int row = wv * 16 + q * 4 + r;
            int col = t * 16 + mrow;
            A[row * LDA + col] = acc[t][r] + b2v[t];
        }
    __syncthreads();

    // ---- LayerNorm stats ----
    {
        int row = tid & 63, seg = tid >> 6;
        float s = 0.f, sq = 0.f;
#pragma unroll
        for (int i = 0; i < 8; ++i) {
            float4 v = *(float4*)&A[row * LDA + seg * 32 + i * 4];
            s += v.x + v.y + v.z + v.w;
            sq += v.x * v.x + v.y * v.y + v.z * v.z + v.w * v.w;
        }
        u.ln.psum[seg][row] = s;
        u.ln.psq[seg][row] = sq;
    }
    __syncthreads();
    if (tid < 64) {
        float s = u.ln.psum[0][tid] + u.ln.psum[1][tid] + u.ln.psum[2][tid] + u.ln.psum[3][tid];
        float sq = u.ln.psq[0][tid] + u.ln.psq[1][tid] + u.ln.psq[2][tid] + u.ln.psq[3][tid];
        float mu = s * (1.f / HDIM);
        float var = sq * (1.f / HDIM) - mu * mu;
        u.ln.lmu[tid] = mu;
        u.ln.linv[tid] = rsqrtf(var + LN_EPS);
    }
    __syncthreads();

    // ---- scale/shift + ReLU ----
    int colbase = (tid * 4) & 127;
    float4 gv = *(const float4*)&g[colbase];
    float4 btv = *(const float4*)&bt[colbase];
#pragma unroll
    for (int i = 0; i < 8; ++i) {
        int row = (tid >> 5) + 8 * i;
        float4 v = *(float4*)&A[row * LDA + colbase];
        float mu = u.ln.lmu[row], inv = u.ln.linv[row];
        float4 o;
        o.x = fmaxf((v.x - mu) * inv * gv.x + btv.x, 0.f);
        o.y = fmaxf((v.y - mu) * inv * gv.y + btv.y, 0.f);
        o.z = fmaxf((v.z - mu) * inv * gv.z + btv.z, 0.f);
        o.w = fmaxf((v.w - mu) * inv * gv.w + btv.w, 0.f);
        if (POOL) {
            *(float4*)&A[row * LDA + colbase] = o;
        } else {
            *(float4*)&xout[(size_t)(node0 + row) * 128 + colbase] = o;
        }
    }

    // ---- fused pooling (layer 2) ----
    if (POOL) {
        __syncthreads();
        if (tid < 128) {
            int col = tid;
            float acc2 = 0.f;
            int cur = bidx[0];
            for (int r = 0; r < 64; ++r) {
                int gi = bidx[r];
                if (gi != cur) {
                    unsafeAtomicAdd(&pool[cur * HDIM + col], acc2);
                    acc2 = 0.f;
                    cur = gi;
                }
                acc2 += A[r * LDA + col];
            }
            unsafeAtomicAdd(&pool[cur * HDIM + col], acc2);
        } else if (tid == 255) {
            int cur = bidx[0], c = 0;
            for (int r = 0; r < 64; ++r) {
                if (bidx[r] != cur) {
                    atomicAdd(&cnt[cur], c);
                    c = 0;
                    cur = bidx[r];
                }
                ++c;
            }
            atomicAdd(&cnt[cur], c);
        }
    }
}

__global__ void pool_final(const float* __restrict__ pool, const int* __restrict__ cnt,
                           float* __restrict__ out) {
    int g = blockIdx.x, j = threadIdx.x;
    float add = pool[g * HDIM + j];
    float c = (float)max(cnt[g], 1);
    out[g * (2 * HDIM) + j] = add / c;
    out[g * (2 * HDIM) + HDIM + j] = add;
}

extern "C" void kernel_launch(void* const* d_in, const int* in_sizes, int n_in,
                              void* d_out, int out_size, void* d_ws, size_t ws_size,
                              hipStream_t stream) {
    const float* x_in = (const float*)d_in[0];
    const int* ei = (const int*)d_in[1];
    const float* ea = (const float*)d_in[2];
    const int* batch = (const int*)d_in[3];
    const float* P[24];
    for (int i = 0; i < 24; ++i) P[i] = (const float*)d_in[4 + i];
    // per layer l (base 8l): 0=ew 1=eb 2=w1 3=b1 4=w2 5=b2 6=g 7=bt

    float* x_a = (float*)d_ws;                            // N*128
    float* x_b = x_a + (size_t)N_NODES * HDIM;            // N*128
    float* pool = x_b + (size_t)N_NODES * HDIM;           // G*128 } zeroed
    int* cnt = (int*)(pool + N_GRAPHS * HDIM);            // G     } together
    int* deg = cnt + N_GRAPHS;                            // N     } (one
    int* cursor = deg + N_NODES;                          // N     } memset)
    int* row_ptr = cursor + N_NODES;                      // N+1
    int* bsums = row_ptr + N_NODES + 1;                   // pad 256
    int* csr_src = bsums + 256;                           // E
    float* csr_val = (float*)(csr_src + N_EDGES);         // E
    short* wp = (short*)(((uintptr_t)(csr_val + N_EDGES) + 15) & ~(uintptr_t)15);
    float* out = (float*)d_out;

    short *w1h[3], *w2h[3];
    for (int l = 0; l < 3; ++l) {
        w1h[l] = wp + (size_t)l * 32768;
        w2h[l] = w1h[l] + 16384;
    }

    // ---- single memset: pool + cnt + deg + cursor ----
    hipMemsetAsync(pool, 0,
                   (N_GRAPHS * HDIM + N_GRAPHS + 2 * N_NODES) * sizeof(int), stream);

    // ---- CSR build ----
    hist_kernel<<<(N_EDGES + 255) / 256, 256, 0, stream>>>(ei, deg);
    scan_phaseA<<<SCAN_BLOCKS, 256, 0, stream>>>(deg, bsums);
    scan_phaseB<<<1, 256, 0, stream>>>(bsums, row_ptr);
    scan_phaseC<<<SCAN_BLOCKS, 256, 0, stream>>>(deg, bsums, row_ptr);
    scatter_kernel<<<(N_EDGES + 255) / 256, 256, 0, stream>>>(ei, ea, row_ptr, cursor, csr_src, csr_val);

    // ---- pack weights (bf16 hi) ----
    pack_w<<<16, 256, 0, stream>>>(P[2], w1h[0], INDIM, 32);
    pack_w<<<64, 256, 0, stream>>>(P[4], w2h[0], 128, 128);
    for (int l = 1; l < 3; ++l) {
        pack_w<<<64, 256, 0, stream>>>(P[8 * l + 2], w1h[l], 128, 128);
        pack_w<<<64, 256, 0, stream>>>(P[8 * l + 4], w2h[l], 128, 128);
    }

    // ---- fused layers ----
    layer_fused<32, false><<<N_NODES / 64, 256, 0, stream>>>(
        x_in, row_ptr, csr_src, csr_val, P[0], P[1],
        w1h[0], P[3], w2h[0], P[5], P[6], P[7], x_a, nullptr, nullptr, nullptr);
    layer_fused<128, false><<<N_NODES / 64, 256, 0, stream>>>(
        x_a, row_ptr, csr_src, csr_val, P[8], P[9],
        w1h[1], P[11], w2h[1], P[13], P[14], P[15], x_b, nullptr, nullptr, nullptr);
    layer_fused<128, true><<<N_NODES / 64, 256, 0, stream>>>(
        x_b, row_ptr, csr_src, csr_val, P[16], P[17],
        w1h[2], P[19], w2h[2], P[21], P[22], P[23], nullptr, batch, pool, cnt);

    pool_final<<<N_GRAPHS, HDIM, 0, stream>>>(pool, cnt, out);
}

// Round 8
// 490.058 us; speedup vs baseline: 1.7162x; 1.1066x over previous
//
#include <hip/hip_runtime.h>

#define N_NODES 200000
#define N_EDGES 400000
#define N_GRAPHS 64
#define HDIM 128
#define INDIM 5
#define LN_EPS 1e-5f
#define LDA 136  // bf16 elements per A row (128 + 8 pad)

typedef __attribute__((ext_vector_type(8))) short short8;
typedef __attribute__((ext_vector_type(4))) float f32x4;

__device__ __forceinline__ unsigned short to_bf(float v) {
    unsigned u = __builtin_bit_cast(unsigned, v);
    return (unsigned short)((u + 0x7FFFu + ((u >> 16) & 1u)) >> 16);
}
__device__ __forceinline__ float bf_lo(unsigned w) { return __builtin_bit_cast(float, w << 16); }
__device__ __forceinline__ float bf_hi(unsigned w) { return __builtin_bit_cast(float, w & 0xFFFF0000u); }
__device__ __forceinline__ float bf2f(unsigned short h) { return __builtin_bit_cast(float, (unsigned)h << 16); }

// ---------------- CSR build ----------------

__global__ void hist_kernel(const int* __restrict__ ei, int* __restrict__ deg) {
    int e = blockIdx.x * blockDim.x + threadIdx.x;
    if (e < N_EDGES) atomicAdd(&deg[ei[N_EDGES + e]], 1);
}

#define SCAN_CHUNK 1024
#define SCAN_BLOCKS ((N_NODES + SCAN_CHUNK - 1) / SCAN_CHUNK)  // 196

__global__ __launch_bounds__(256) void scan_phaseA(const int* __restrict__ deg, int* __restrict__ bsums) {
    __shared__ int red[256];
    int t = threadIdx.x;
    int base = blockIdx.x * SCAN_CHUNK + t * 4;
    int s = 0;
#pragma unroll
    for (int k = 0; k < 4; ++k) {
        int i = base + k;
        s += (i < N_NODES) ? deg[i] : 0;
    }
    red[t] = s;
    __syncthreads();
    for (int off = 128; off; off >>= 1) {
        if (t < off) red[t] += red[t + off];
        __syncthreads();
    }
    if (t == 0) bsums[blockIdx.x] = red[0];
}

__global__ __launch_bounds__(256) void scan_phaseB(int* __restrict__ bsums, int* __restrict__ row_ptr) {
    __shared__ int s[256];
    int t = threadIdx.x;
    int v = (t < SCAN_BLOCKS) ? bsums[t] : 0;
    s[t] = v;
    __syncthreads();
    for (int off = 1; off < 256; off <<= 1) {
        int add = (t >= off) ? s[t - off] : 0;
        __syncthreads();
        s[t] += add;
        __syncthreads();
    }
    if (t < SCAN_BLOCKS) bsums[t] = s[t] - v;  // exclusive
    if (t == SCAN_BLOCKS - 1) row_ptr[N_NODES] = s[t];
}

__global__ __launch_bounds__(256) void scan_phaseC(const int* __restrict__ deg,
                                                   const int* __restrict__ bsums,
                                                   int* __restrict__ row_ptr) {
    __shared__ int ts[256];
    int t = threadIdx.x;
    int base = blockIdx.x * SCAN_CHUNK + t * 4;
    int v[4];
    int s = 0;
#pragma unroll
    for (int k = 0; k < 4; ++k) {
        int i = base + k;
        v[k] = (i < N_NODES) ? deg[i] : 0;
        s += v[k];
    }
    ts[t] = s;
    __syncthreads();
    for (int off = 1; off < 256; off <<= 1) {
        int add = (t >= off) ? ts[t - off] : 0;
        __syncthreads();
        ts[t] += add;
        __syncthreads();
    }
    int run = bsums[blockIdx.x] + ts[t] - s;
#pragma unroll
    for (int k = 0; k < 4; ++k) {
        int i = base + k;
        if (i < N_NODES) row_ptr[i] = run;
        run += v[k];
    }
}

__global__ void scatter_kernel(const int* __restrict__ ei, const float* __restrict__ ea,
                               const int* __restrict__ row_ptr, int* __restrict__ cursor,
                               int* __restrict__ csr_src, float* __restrict__ csr_val) {
    int e = blockIdx.x * blockDim.x + threadIdx.x;
    if (e >= N_EDGES) return;
    int d = ei[N_EDGES + e];
    int pos = atomicAdd(&cursor[d], 1);
    int slot = row_ptr[d] + pos;
    csr_src[slot] = ei[e];
    csr_val[slot] = ea[e];
}

// ---------------- Weight packing into MFMA B-fragment order (bf16) ----------------
__global__ void pack_w(const float* __restrict__ W, short* __restrict__ hi, int din, int KP) {
    int idx = blockIdx.x * 256 + threadIdx.x;
    if (idx >= KP * 128) return;
    int j = idx & 7;
    int lane = (idx >> 3) & 63;
    int rest = idx >> 9;
    int KS = KP >> 5;
    int kstep = rest % KS;
    int tile = rest / KS;
    int k = kstep * 32 + ((lane >> 4) * 8) + j;
    int n = tile * 16 + (lane & 15);
    float v = (k < din) ? W[k * 128 + n] : 0.f;
    hi[idx] = (short)to_bf(v);
}

// ---------------- Fused layer: gather + MFMA MLP + reg-LN + ReLU (+pool) ----------------
template <int KP1, bool POOL>
__global__ __launch_bounds__(256, 5) void layer_fused(
    const void* __restrict__ xin_v, const int* __restrict__ row_ptr,
    const int* __restrict__ csr_src, const float* __restrict__ csr_val,
    const float* __restrict__ ew, const float* __restrict__ eb,
    const short* __restrict__ w1h, const float* __restrict__ b1,
    const short* __restrict__ w2h, const float* __restrict__ b2,
    const float* __restrict__ g, const float* __restrict__ bt,
    unsigned short* __restrict__ xout,
    const int* __restrict__ batch, float* __restrict__ pool, int* __restrict__ cnt) {
    __shared__ __align__(16) unsigned short A16[64 * LDA];
    __shared__ int bidx[64];
    union Scratch {
        float eweb[256];                 // [0..127]=ew, [128..255]=eb  (din=128 path)
        float part[64][2][INDIM];        // layer-0 gather partials
    };
    __shared__ Scratch u;

    int tid = threadIdx.x;
    int node0 = blockIdx.x * 64;

    if (KP1 == 128) {
        const unsigned short* xin = (const unsigned short*)xin_v;
        // stage ew/eb to LDS
        if (tid < 32) ((float4*)u.eweb)[tid] = ((const float4*)ew)[tid];
        else if (tid < 64) ((float4*)u.eweb)[tid] = ((const float4*)eb)[tid - 32];
        if (POOL && tid >= 64 && tid < 128) bidx[tid - 64] = batch[node0 + tid - 64];

        // thread = (row, 32-channel quarter); f32 accumulators in registers
        int row = tid >> 2, qt = tid & 3, c0 = qt * 32;
        int node = node0 + row;
        float acc[32];
        {
            const uint4* xn = (const uint4*)(xin + (size_t)node * 128 + c0);
            uint4 uv[4];
#pragma unroll
            for (int j = 0; j < 4; ++j) uv[j] = xn[j];
            unsigned wds[16] = {uv[0].x, uv[0].y, uv[0].z, uv[0].w,
                                uv[1].x, uv[1].y, uv[1].z, uv[1].w,
                                uv[2].x, uv[2].y, uv[2].z, uv[2].w,
                                uv[3].x, uv[3].y, uv[3].z, uv[3].w};
#pragma unroll
            for (int i = 0; i < 16; ++i) {
                acc[2 * i] = bf_lo(wds[i]);
                acc[2 * i + 1] = bf_hi(wds[i]);
            }
        }
        int beg = row_ptr[node], end = row_ptr[node + 1];
        __syncthreads();  // eweb ready

        for (int e = beg; e < end; ++e) {
            int s = csr_src[e];
            float a = csr_val[e];
            const uint4* xs = (const uint4*)(xin + (size_t)s * 128 + c0);
            uint4 uv[4];
#pragma unroll
            for (int j = 0; j < 4; ++j) uv[j] = xs[j];
            unsigned wds[16] = {uv[0].x, uv[0].y, uv[0].z, uv[0].w,
                                uv[1].x, uv[1].y, uv[1].z, uv[1].w,
                                uv[2].x, uv[2].y, uv[2].z, uv[2].w,
                                uv[3].x, uv[3].y, uv[3].z, uv[3].w};
#pragma unroll
            for (int i = 0; i < 16; ++i) {
                int cA = c0 + 2 * i, cB = cA + 1;
                acc[2 * i] += fmaxf(fmaf(a, u.eweb[cA], bf_lo(wds[i]) + u.eweb[128 + cA]), 0.f);
                acc[2 * i + 1] += fmaxf(fmaf(a, u.eweb[cB], bf_hi(wds[i]) + u.eweb[128 + cB]), 0.f);
            }
        }
        // store bf16 A row segment (wave-local: rows wv*16.. are written by tids wv*64..)
        unsigned* Ar = (unsigned*)&A16[row * LDA + c0];
#pragma unroll
        for (int i = 0; i < 16; ++i)
            Ar[i] = (unsigned)to_bf(acc[2 * i]) | ((unsigned)to_bf(acc[2 * i + 1]) << 16);
    } else {
        // layer 0 (din=5): 2 threads/row split the edge list; register partials
        const float* xinf = (const float*)xin_v;
        int row = tid >> 2, qt = tid & 3;
        int node = node0 + row;
        if (qt < 2) {
            float w[INDIM], b[INDIM], acc[INDIM];
#pragma unroll
            for (int j = 0; j < INDIM; ++j) {
                w[j] = ew[j];
                b[j] = eb[j];
                acc[j] = 0.f;
            }
            int beg = row_ptr[node], end = row_ptr[node + 1];
            for (int e = beg + qt; e < end; e += 2) {
                int s = csr_src[e];
                float a = csr_val[e];
#pragma unroll
                for (int j = 0; j < INDIM; ++j)
                    acc[j] += fmaxf(fmaf(a, w[j], xinf[s * INDIM + j] + b[j]), 0.f);
            }
#pragma unroll
            for (int j = 0; j < INDIM; ++j) u.part[row][qt][j] = acc[j];
        }
        __syncthreads();
        if (tid < 64) {
#pragma unroll
            for (int j = 0; j < INDIM; ++j) {
                float v = xinf[(node0 + tid) * INDIM + j] + u.part[tid][0][j] + u.part[tid][1][j];
                A16[tid * LDA + j] = to_bf(v);
            }
#pragma unroll
            for (int j = INDIM; j < 32; ++j) A16[tid * LDA + j] = 0;
        }
        __syncthreads();  // cross-wave A writes
    }

    // ---- MFMA MLP ----
    int wv = tid >> 6, lane = tid & 63;
    int mrow = lane & 15, q = lane >> 4;
    int arow = wv * 16 + mrow;

    const short8* w1p = (const short8*)w1h;
    const short8* w2p = (const short8*)w2h;

    f32x4 acc2[8];
#pragma unroll
    for (int t = 0; t < 8; ++t) acc2[t] = (f32x4){0.f, 0.f, 0.f, 0.f};
    constexpr int KS1 = KP1 / 32;
#pragma unroll
    for (int ks = 0; ks < KS1; ++ks) {
        short8 bh[8];
#pragma unroll
        for (int t = 0; t < 8; ++t) bh[t] = w1p[((size_t)t * KS1 + ks) * 64 + lane];
        short8 ah = *(const short8*)&A16[arow * LDA + ks * 32 + q * 8];
#pragma unroll
        for (int t = 0; t < 8; ++t)
            acc2[t] = __builtin_amdgcn_mfma_f32_16x16x32_bf16(ah, bh[t], acc2[t], 0, 0, 0);
    }
    // t1 = relu(acc + b1) -> bf16 A (wave-local rows)
    {
        float b1v[8];
#pragma unroll
        for (int t = 0; t < 8; ++t) b1v[t] = b1[t * 16 + mrow];
#pragma unroll
        for (int t = 0; t < 8; ++t)
#pragma unroll
            for (int r = 0; r < 4; ++r) {
                int rrow = wv * 16 + q * 4 + r;
                int col = t * 16 + mrow;
                A16[rrow * LDA + col] = to_bf(fmaxf(acc2[t][r] + b1v[t], 0.f));
            }
    }

    // GEMM2 (K = 128)
#pragma unroll
    for (int t = 0; t < 8; ++t) acc2[t] = (f32x4){0.f, 0.f, 0.f, 0.f};
#pragma unroll
    for (int ks = 0; ks < 4; ++ks) {
        short8 bh[8];
#pragma unroll
        for (int t = 0; t < 8; ++t) bh[t] = w2p[((size_t)t * 4 + ks) * 64 + lane];
        short8 ah = *(const short8*)&A16[arow * LDA + ks * 32 + q * 8];
#pragma unroll
        for (int t = 0; t < 8; ++t)
            acc2[t] = __builtin_amdgcn_mfma_f32_16x16x32_bf16(ah, bh[t], acc2[t], 0, 0, 0);
    }

    // ---- LayerNorm in registers (rows live in 16-lane groups) ----
    float s4[4] = {0.f, 0.f, 0.f, 0.f}, q4[4] = {0.f, 0.f, 0.f, 0.f};
    {
        float b2v[8];
#pragma unroll
        for (int t = 0; t < 8; ++t) b2v[t] = b2[t * 16 + mrow];
#pragma unroll
        for (int t = 0; t < 8; ++t)
#pragma unroll
            for (int r = 0; r < 4; ++r) {
                float v = acc2[t][r] + b2v[t];
                acc2[t][r] = v;
                s4[r] += v;
                q4[r] += v * v;
            }
    }
#pragma unroll
    for (int m = 1; m <= 8; m <<= 1) {
#pragma unroll
        for (int r = 0; r < 4; ++r) {
            s4[r] += __shfl_xor(s4[r], m, 64);
            q4[r] += __shfl_xor(q4[r], m, 64);
        }
    }
    float mu[4], inv[4];
#pragma unroll
    for (int r = 0; r < 4; ++r) {
        mu[r] = s4[r] * (1.f / HDIM);
        float var = q4[r] * (1.f / HDIM) - mu[r] * mu[r];
        inv[r] = rsqrtf(var + LN_EPS);
    }
    float gv[8], btv[8];
#pragma unroll
    for (int t = 0; t < 8; ++t) {
        gv[t] = g[t * 16 + mrow];
        btv[t] = bt[t * 16 + mrow];
    }

    if (!POOL) {
#pragma unroll
        for (int t = 0; t < 8; ++t)
#pragma unroll
            for (int r = 0; r < 4; ++r) {
                int rrow = wv * 16 + q * 4 + r;
                int col = t * 16 + mrow;
                float o = fmaxf((acc2[t][r] - mu[r]) * inv[r] * gv[t] + btv[t], 0.f);
                xout[(size_t)(node0 + rrow) * 128 + col] = to_bf(o);
            }
    } else {
#pragma unroll
        for (int t = 0; t < 8; ++t)
#pragma unroll
            for (int r = 0; r < 4; ++r) {
                int rrow = wv * 16 + q * 4 + r;
                int col = t * 16 + mrow;
                float o = fmaxf((acc2[t][r] - mu[r]) * inv[r] * gv[t] + btv[t], 0.f);
                A16[rrow * LDA + col] = to_bf(o);
            }
        __syncthreads();
        if (tid < 128) {
            int col = tid;
            float accp = 0.f;
            int cur = bidx[0];
            for (int r = 0; r < 64; ++r) {
                int gi = bidx[r];
                if (gi != cur) {
                    unsafeAtomicAdd(&pool[cur * HDIM + col], accp);
                    accp = 0.f;
                    cur = gi;
                }
                accp += bf2f(A16[r * LDA + col]);
            }
            unsafeAtomicAdd(&pool[cur * HDIM + col], accp);
        } else if (tid == 255) {
            int cur = bidx[0], c = 0;
            for (int r = 0; r < 64; ++r) {
                if (bidx[r] != cur) {
                    atomicAdd(&cnt[cur], c);
                    c = 0;
                    cur = bidx[r];
                }
                ++c;
            }
            atomicAdd(&cnt[cur], c);
        }
    }
}

__global__ void pool_final(const float* __restrict__ pool, const int* __restrict__ cnt,
                           float* __restrict__ out) {
    int g = blockIdx.x, j = threadIdx.x;
    float add = pool[g * HDIM + j];
    float c = (float)max(cnt[g], 1);
    out[g * (2 * HDIM) + j] = add / c;
    out[g * (2 * HDIM) + HDIM + j] = add;
}

extern "C" void kernel_launch(void* const* d_in, const int* in_sizes, int n_in,
                              void* d_out, int out_size, void* d_ws, size_t ws_size,
                              hipStream_t stream) {
    const float* x_in = (const float*)d_in[0];
    const int* ei = (const int*)d_in[1];
    const float* ea = (const float*)d_in[2];
    const int* batch = (const int*)d_in[3];
    const float* P[24];
    for (int i = 0; i < 24; ++i) P[i] = (const float*)d_in[4 + i];
    // per layer l (base 8l): 0=ew 1=eb 2=w1 3=b1 4=w2 5=b2 6=g 7=bt

    unsigned short* x_a = (unsigned short*)d_ws;                 // N*128 bf16
    unsigned short* x_b = x_a + (size_t)N_NODES * HDIM;          // N*128 bf16
    float* pool = (float*)(x_b + (size_t)N_NODES * HDIM);        // G*128 } zeroed
    int* cnt = (int*)(pool + N_GRAPHS * HDIM);                   // G     } together
    int* deg = cnt + N_GRAPHS;                                   // N
    int* cursor = deg + N_NODES;                                 // N
    int* row_ptr = cursor + N_NODES;                             // N+1
    int* bsums = row_ptr + N_NODES + 1;                          // pad 256
    int* csr_src = bsums + 256;                                  // E
    float* csr_val = (float*)(csr_src + N_EDGES);                // E
    short* wp = (short*)(((uintptr_t)(csr_val + N_EDGES) + 15) & ~(uintptr_t)15);
    float* out = (float*)d_out;

    short *w1h[3], *w2h[3];
    for (int l = 0; l < 3; ++l) {
        w1h[l] = wp + (size_t)l * 32768;
        w2h[l] = w1h[l] + 16384;
    }

    // ---- single memset: pool + cnt + deg + cursor ----
    hipMemsetAsync(pool, 0,
                   (N_GRAPHS * HDIM + N_GRAPHS + 2 * N_NODES) * sizeof(int), stream);

    // ---- CSR build ----
    hist_kernel<<<(N_EDGES + 255) / 256, 256, 0, stream>>>(ei, deg);
    scan_phaseA<<<SCAN_BLOCKS, 256, 0, stream>>>(deg, bsums);
    scan_phaseB<<<1, 256, 0, stream>>>(bsums, row_ptr);
    scan_phaseC<<<SCAN_BLOCKS, 256, 0, stream>>>(deg, bsums, row_ptr);
    scatter_kernel<<<(N_EDGES + 255) / 256, 256, 0, stream>>>(ei, ea, row_ptr, cursor, csr_src, csr_val);

    // ---- pack weights (bf16) ----
    pack_w<<<16, 256, 0, stream>>>(P[2], w1h[0], INDIM, 32);
    pack_w<<<64, 256, 0, stream>>>(P[4], w2h[0], 128, 128);
    for (int l = 1; l < 3; ++l) {
        pack_w<<<64, 256, 0, stream>>>(P[8 * l + 2], w1h[l], 128, 128);
        pack_w<<<64, 256, 0, stream>>>(P[8 * l + 4], w2h[l], 128, 128);
    }

    // ---- fused layers ----
    layer_fused<32, false><<<N_NODES / 64, 256, 0, stream>>>(
        x_in, row_ptr, csr_src, csr_val, P[0], P[1],
        w1h[0], P[3], w2h[0], P[5], P[6], P[7], x_a, nullptr, nullptr, nullptr);
    layer_fused<128, false><<<N_NODES / 64, 256, 0, stream>>>(
        x_a, row_ptr, csr_src, csr_val, P[8], P[9],
        w1h[1], P[11], w2h[1], P[13], P[14], P[15], x_b, nullptr, nullptr, nullptr);
    layer_fused<128, true><<<N_NODES / 64, 256, 0, stream>>>(
        x_b, row_ptr, csr_src, csr_val, P[16], P[17],
        w1h[2], P[19], w2h[2], P[21], P[22], P[23], nullptr, batch, pool, cnt);

    pool_final<<<N_GRAPHS, HDIM, 0, stream>>>(pool, cnt, out);
}